// Round 3
// baseline (66.135 us; speedup 1.0000x reference)
//
#include <hip/hip_runtime.h>
#include <hip/hip_bf16.h>

typedef __bf16 bf16x8 __attribute__((ext_vector_type(8)));
typedef float  f32x4  __attribute__((ext_vector_type(4)));

#define B_ROWS 8192
#define IN_DIM 256
#define OUT_DIM 32
#define NCLS 50
#define INV_T (1.0f / 0.6f)

#define CVT_BLOCKS 1024  // 8192*256 / (256 threads * 8 elems)
#define CGRP 5           // classes per block
#define NGRP 10          // 50 / CGRP
#define MBLKS 128        // 8192 / 64 rows per block

// Fused prep: blocks [0,1024) convert x f32->bf16; blocks [1024,1074) build
// W'[c,o,i] = bf16(W[c,o,i] * alpha_norm[c,i]),
// alpha_norm[c,i] = exp((gamma[c,i]-max_i gamma)/T), gamma = sum_o |W|.
__global__ __launch_bounds__(256) void prep(const float* __restrict__ x,
                                            const float* __restrict__ w,
                                            __bf16* __restrict__ xb,
                                            __bf16* __restrict__ wb) {
    int bid = blockIdx.x;
    if (bid < CVT_BLOCKS) {
        int i = (bid * 256 + threadIdx.x) * 8;
        float4 v0 = *reinterpret_cast<const float4*>(x + i);
        float4 v1 = *reinterpret_cast<const float4*>(x + i + 4);
        bf16x8 r;
        r[0] = (__bf16)v0.x; r[1] = (__bf16)v0.y; r[2] = (__bf16)v0.z; r[3] = (__bf16)v0.w;
        r[4] = (__bf16)v1.x; r[5] = (__bf16)v1.y; r[6] = (__bf16)v1.z; r[7] = (__bf16)v1.w;
        *reinterpret_cast<bf16x8*>(xb + i) = r;
    } else {
        int c = bid - CVT_BLOCKS;
        int i = threadIdx.x;  // IN index
        const float* wc = w + (size_t)c * OUT_DIM * IN_DIM;
        float g = 0.f;
#pragma unroll
        for (int o = 0; o < OUT_DIM; ++o) g += fabsf(wc[o * IN_DIM + i]);
        float m = g;
#pragma unroll
        for (int s = 1; s < 64; s <<= 1) m = fmaxf(m, __shfl_xor(m, s));
        __shared__ float wm[4];
        if ((threadIdx.x & 63) == 0) wm[threadIdx.x >> 6] = m;
        __syncthreads();
        m = fmaxf(fmaxf(wm[0], wm[1]), fmaxf(wm[2], wm[3]));
        float an = __expf((g - m) * INV_T);
        __bf16* wbc = wb + (size_t)c * OUT_DIM * IN_DIM;
#pragma unroll
        for (int o = 0; o < OUT_DIM; ++o)
            wbc[o * IN_DIM + i] = (__bf16)(wc[o * IN_DIM + i] * an);
    }
}

// Batched GEMM: out[b, c, o] = sum_i xb[b,i]*wb[c,o,i] + bias[c,o]
// grid = 128 m-blocks * 10 class-groups. Block = 4 waves; wave owns 16 rows,
// A (x) fragments register-resident (8x bf16x8), reused across CGRP classes.
// MFMA operands swapped: mfma(W_frag, x_frag) -> D col(lane&15)=b, row=o.
__global__ __launch_bounds__(256) void gemm(const __bf16* __restrict__ xb,
                                            const __bf16* __restrict__ wb,
                                            const float* __restrict__ bias,
                                            float* __restrict__ out) {
    int bid = blockIdx.x;
    int mblk = bid & (MBLKS - 1);
    int cg = bid >> 7;            // 0..9
    int c0 = cg * CGRP;
    int lane = threadIdx.x & 63;
    int wave = threadIdx.x >> 6;
    int m_base = mblk * 64 + wave * 16;
    int l15 = lane & 15;
    int g = lane >> 4;
    int obase = g * 4;

    // A fragments (x as operand1): lane holds x[b=m_base+l15][k=g*8+j+32*kk]
    const __bf16* ap = xb + (size_t)(m_base + l15) * IN_DIM + g * 8;
    bf16x8 afrag[8];
#pragma unroll
    for (int kk = 0; kk < 8; ++kk)
        afrag[kk] = *reinterpret_cast<const bf16x8*>(ap + kk * 32);

    float* orow = out + (size_t)(m_base + l15) * (NCLS * OUT_DIM);

#pragma unroll
    for (int ci = 0; ci < CGRP; ++ci) {
        int c = c0 + ci;
        const __bf16* bp = wb + ((size_t)c * OUT_DIM + l15) * IN_DIM + g * 8;
        f32x4 acc0 = {0.f, 0.f, 0.f, 0.f};
        f32x4 acc1 = {0.f, 0.f, 0.f, 0.f};
#pragma unroll
        for (int kk = 0; kk < 8; ++kk) {
            bf16x8 w0 = *reinterpret_cast<const bf16x8*>(bp + kk * 32);
            bf16x8 w1 = *reinterpret_cast<const bf16x8*>(bp + 16 * IN_DIM + kk * 32);
            acc0 = __builtin_amdgcn_mfma_f32_16x16x32_bf16(w0, afrag[kk], acc0, 0, 0, 0);
            acc1 = __builtin_amdgcn_mfma_f32_16x16x32_bf16(w1, afrag[kk], acc1, 0, 0, 0);
        }
        float4 bv0 = *reinterpret_cast<const float4*>(bias + c * OUT_DIM + obase);
        float4 bv1 = *reinterpret_cast<const float4*>(bias + c * OUT_DIM + 16 + obase);
        acc0[0] += bv0.x; acc0[1] += bv0.y; acc0[2] += bv0.z; acc0[3] += bv0.w;
        acc1[0] += bv1.x; acc1[1] += bv1.y; acc1[2] += bv1.z; acc1[3] += bv1.w;
        float* p = orow + c * OUT_DIM;
        *reinterpret_cast<f32x4*>(p + obase) = acc0;
        *reinterpret_cast<f32x4*>(p + 16 + obase) = acc1;
    }
}

extern "C" void kernel_launch(void* const* d_in, const int* in_sizes, int n_in,
                              void* d_out, int out_size, void* d_ws, size_t ws_size,
                              hipStream_t stream) {
    const float* x    = (const float*)d_in[0];
    const float* w    = (const float*)d_in[1];
    const float* bias = (const float*)d_in[2];
    float* out = (float*)d_out;

    __bf16* xb = (__bf16*)d_ws;                       // 8192*256 bf16 = 4 MB
    __bf16* wb = xb + (size_t)B_ROWS * IN_DIM;        // 50*32*256 bf16 = 0.8 MB

    prep<<<CVT_BLOCKS + NCLS, 256, 0, stream>>>(x, w, xb, wb);
    gemm<<<MBLKS * NGRP, 256, 0, stream>>>(xb, wb, bias, out);
}